// Round 9
// baseline (882.781 us; speedup 1.0000x reference)
//
#include <hip/hip_runtime.h>
#include <math.h>

// LocalGatedKL on MI355X — SINGLE fused persistent kernel (512 blocks x 256 thr,
// 2 blocks/CU by LDS => all co-resident), manual device-scope grid barriers.
// Stages: G0 weight-transpose+seed | G1 gemm_t (conv commuted before resize, K-split 4)
//         G2 bilinear 32->64 + channel-normalize | G3 sobel+minmax  G4 gemm_s+normalize
//         G5 fused s+t affinities + log_softmax + gating + KL + reduction | finalize.
// Barriers are poison-tolerant (CAS 0xAAAAAAAA->0), epoch-released, self-resetting.

#define WS_T32   0u
#define WS_TN    2097152u
#define WS_SN    4194304u
#define WS_TM    6291456u
#define WS_MAG   6324224u
#define WS_WTT   6356992u     // 512*64
#define WS_WST   6389760u     // 256*64
#define WS_MNMX  6406144u     // 16 uints
#define WS_BAR   6406160u     // 10 uints: 5 barriers x {cnt, epoch}
#define WS_ACC   6406172u     // 2 doubles (byte 25624688, 8B aligned)

#define NBLK 512
#define NTHR 256

static __device__ __forceinline__ int reflect_idx(int i, int n) {
  if (i < 0) i = -i;
  if (i >= n) i = 2 * n - 2 - i;
  return i;
}

// Grid barrier: tolerant of 0xAA poison and of stale state (self-resets cnt; epoch
// comparison is value-agnostic). Device-scope atomics cross XCDs.
static __device__ __forceinline__ void gridbar(unsigned int* bar, int slot) {
  __syncthreads();
  if (threadIdx.x == 0) {
    unsigned int* cnt = bar + slot * 2;
    unsigned int* ep  = bar + slot * 2 + 1;
    __threadfence();
    atomicCAS(cnt, 0xAAAAAAAAu, 0u);               // heal poison (idempotent)
    unsigned int e0 = __hip_atomic_load(ep, __ATOMIC_RELAXED, __HIP_MEMORY_SCOPE_AGENT);
    unsigned int prev = __hip_atomic_fetch_add(cnt, 1u, __ATOMIC_ACQ_REL, __HIP_MEMORY_SCOPE_AGENT);
    if (prev == (unsigned int)(NBLK - 1)) {
      __hip_atomic_store(cnt, 0u, __ATOMIC_RELAXED, __HIP_MEMORY_SCOPE_AGENT);
      __hip_atomic_fetch_add(ep, 1u, __ATOMIC_RELEASE, __HIP_MEMORY_SCOPE_AGENT);
    } else {
      long spins = 0;
      while (__hip_atomic_load(ep, __ATOMIC_ACQUIRE, __HIP_MEMORY_SCOPE_AGENT) == e0) {
        __builtin_amdgcn_s_sleep(2);
        if (++spins > (1L << 22)) break;           // failsafe; never expected
      }
    }
    __threadfence();
  }
  __syncthreads();
}

// --- GEMM building blocks: 16 outs/wave, groups of 4 channels, even/odd pipeline (no reg copies).
static __device__ __forceinline__ void loadw16(float4 w[16], const float* wb, int g) {
#pragma unroll
  for (int cc = 0; cc < 4; ++cc)
#pragma unroll
    for (int j = 0; j < 4; ++j)
      w[cc * 4 + j] = *(const float4*)(wb + (g * 4 + cc) * 64 + j * 4);
}
template <int STRIDE>
static __device__ __forceinline__ void loadv4(float v[4], const float* fb, int g) {
#pragma unroll
  for (int cc = 0; cc < 4; ++cc) v[cc] = fb[(size_t)(g * 4 + cc) * STRIDE];
}
static __device__ __forceinline__ void fma64(float4 acc[4], const float4 w[16], const float v[4]) {
#pragma unroll
  for (int cc = 0; cc < 4; ++cc)
#pragma unroll
    for (int j = 0; j < 4; ++j) {
      acc[j].x += w[cc * 4 + j].x * v[cc];
      acc[j].y += w[cc * 4 + j].y * v[cc];
      acc[j].z += w[cc * 4 + j].z * v[cc];
      acc[j].w += w[cc * 4 + j].w * v[cc];
    }
}
template <int NG, int STRIDE>
static __device__ __forceinline__ void gemm_core(const float* fb, const float* wb, float4 acc[4]) {
  float4 wA[16], wB[16];
  float vA[4], vB[4];
  loadw16(wA, wb, 0);
  loadv4<STRIDE>(vA, fb, 0);
#pragma unroll 1
  for (int g = 0; g + 1 < NG; g += 2) {
    loadw16(wB, wb, g + 1);
    loadv4<STRIDE>(vB, fb, g + 1);
    fma64(acc, wA, vA);
    int gn = (g + 2 < NG) ? (g + 2) : (NG - 1);   // clamped prefetch (redundant last load, in-bounds)
    loadw16(wA, wb, gn);
    loadv4<STRIDE>(vA, fb, gn);
    fma64(acc, wB, vB);
  }
}

// 24-window partial affinities over a [144][68]-swizzled LDS tile (16 ch slice).
static __device__ __forceinline__ void windows24(const float* flb, int base, int cbase, float* aff) {
  float4 cv[4];
  {
    int cp = base + 26;
    int cs = (((cp * 17) >> 3) & 3) << 2;
    const float* crow = flb + cp * 68;
#pragma unroll
    for (int j = 0; j < 4; ++j) cv[j] = *(const float4*)(crow + ((cbase + 4 * j) ^ cs));
  }
  int n = 0;
#pragma unroll
  for (int dy = 0; dy < 5; dy++)
#pragma unroll
    for (int dx = 0; dx < 5; dx++) {
      if (dy == 2 && dx == 2) continue;
      int pp = base + dy * 12 + dx;
      int sw2 = (((pp * 17) >> 3) & 3) << 2;
      const float* rowp = flb + pp * 68;
      float4 q0 = *(const float4*)(rowp + ((cbase + 0) ^ sw2));
      float4 q1 = *(const float4*)(rowp + ((cbase + 4) ^ sw2));
      float4 q2 = *(const float4*)(rowp + ((cbase + 8) ^ sw2));
      float4 q3 = *(const float4*)(rowp + ((cbase + 12) ^ sw2));
      aff[n] = cv[0].x * q0.x + cv[0].y * q0.y + cv[0].z * q0.z + cv[0].w * q0.w
             + cv[1].x * q1.x + cv[1].y * q1.y + cv[1].z * q1.z + cv[1].w * q1.w
             + cv[2].x * q2.x + cv[2].y * q2.y + cv[2].z * q2.z + cv[2].w * q2.w
             + cv[3].x * q3.x + cv[3].y * q3.y + cv[3].z * q3.z + cv[3].w * q3.w;
      n++;
    }
}

__global__ __launch_bounds__(NTHR, 2) void k_fused(const float* __restrict__ fs3,
                                                   const float* __restrict__ ft,
                                                   const float* __restrict__ Ws,
                                                   const float* __restrict__ Wt,
                                                   float* __restrict__ wsf,
                                                   float* __restrict__ out) {
  __shared__ __align__(16) float fl[2 * 144 * 68];   // 78.3 KB -> exactly 2 blocks/CU
  float* t32 = wsf + WS_T32;
  float* tn  = wsf + WS_TN;
  float* sn  = wsf + WS_SN;
  float* tm  = wsf + WS_TM;
  float* mag = wsf + WS_MAG;
  float* WtT = wsf + WS_WTT;
  float* WsT = wsf + WS_WST;
  unsigned int* mnmx = (unsigned int*)(wsf + WS_MNMX);
  unsigned int* bar  = (unsigned int*)(wsf + WS_BAR);
  double* acc = (double*)(wsf + WS_ACC);

  const int tid = threadIdx.x;
  const int bx = blockIdx.x;
  const int g = bx * NTHR + tid;

  // ---- G0: weight transposes (WtT[c][64], WsT[c][64]) + seeds ----
  if (g < 32768) {
    int c = g >> 6, o = g & 63;
    WtT[g] = Wt[o * 512 + c];
  } else if (g < 49152) {
    int j = g - 32768;
    int c = j >> 6, o = j & 63;
    WsT[j] = Ws[o * 256 + c];
  }
  if (bx == 0) {
    if (tid < 8) mnmx[tid] = 0x7F800000u;            // +inf (uint order == float order, m>=0)
    else if (tid < 16) mnmx[tid] = 0u;
    else if (tid == 16) acc[0] = 0.0;
    else if (tid == 17) acc[1] = 0.0;
  }
  gridbar(bar, 0);

  // ---- G1: t32 = Wt @ ft at 32x32, K-split 4, channel-major partials ----
  {
    const int w = tid >> 6, ln = tid & 63;
    const int o0 = w * 16;
    const int pxt = bx & 127, kpart = bx >> 7;
    const int b = pxt >> 4;
    const int pixl = (pxt & 15) * 64 + ln;
    const float* fb = ft + (size_t)b * 524288 + (size_t)kpart * 131072 + pixl;
    const float* wb = WtT + kpart * 8192 + o0;
    float4 a4[4];
#pragma unroll
    for (int j = 0; j < 4; ++j) a4[j] = make_float4(0.f, 0.f, 0.f, 0.f);
    gemm_core<32, 1024>(fb, wb, a4);
    float* ob = t32 + ((size_t)(kpart * 8 + b) * 64 + o0) * 1024 + pixl;
#pragma unroll
    for (int j = 0; j < 4; ++j) {
      ob[(size_t)(4 * j + 0) * 1024] = a4[j].x;
      ob[(size_t)(4 * j + 1) * 1024] = a4[j].y;
      ob[(size_t)(4 * j + 2) * 1024] = a4[j].z;
      ob[(size_t)(4 * j + 3) * 1024] = a4[j].w;
    }
  }
  gridbar(bar, 1);

  // ---- G2: bilinear 32->64 (half-pixel+clamp), sum 4 partials, normalize -> tn, mean -> tm ----
  {
    const int p = g >> 2, q = g & 3;
    const int b = p >> 12, pix = p & 4095;
    const int y = pix >> 6, x = pix & 63;
    float fy = 0.5f * y - 0.25f, fx = 0.5f * x - 0.25f;
    int y0f = (int)floorf(fy), x0f = (int)floorf(fx);
    float wy = fy - (float)y0f, wx = fx - (float)x0f;
    int y1 = min(y0f + 1, 31), x1 = min(x0f + 1, 31);
    int y0 = max(y0f, 0), x0 = max(x0f, 0);
    const int ip[4] = {y0 * 32 + x0, y0 * 32 + x1, y1 * 32 + x0, y1 * 32 + x1};
    const float wg[4] = {(1.f - wy) * (1.f - wx), (1.f - wy) * wx, wy * (1.f - wx), wy * wx};
    float v[16];
#pragma unroll
    for (int i = 0; i < 16; i++) v[i] = 0.f;
#pragma unroll
    for (int cr = 0; cr < 4; cr++) {
      float wq = wg[cr];
#pragma unroll
      for (int part = 0; part < 4; part++) {
        const float* base = t32 + (((size_t)part * 8 + b) * 64 + q * 16) * 1024 + ip[cr];
#pragma unroll
        for (int c = 0; c < 16; c++) v[c] += wq * base[(size_t)c * 1024];
      }
    }
    float sum = 0.f, ssq = 0.f;
#pragma unroll
    for (int i = 0; i < 16; i++) { sum += v[i]; ssq += v[i] * v[i]; }
    float s1 = sum + __shfl_xor(sum, 1);  float sumf = s1 + __shfl_xor(s1, 2);
    float q1 = ssq + __shfl_xor(ssq, 1);  float ssqf = q1 + __shfl_xor(q1, 2);
    float rn = 1.f / fmaxf(sqrtf(ssqf), 1e-12f);
    float* tp = tn + ((size_t)b * 4096 + pix) * 64 + q * 16;
#pragma unroll
    for (int j = 0; j < 4; j++)
      *(float4*)(tp + 4 * j) = make_float4(v[4 * j] * rn, v[4 * j + 1] * rn,
                                           v[4 * j + 2] * rn, v[4 * j + 3] * rn);
    if (q == 0) tm[p] = sumf * (1.f / 64.f);
  }
  gridbar(bar, 2);

  // ---- G3: sobel + per-image min/max (first 32768 threads) ----
  if (g < 32768) {
    const int b = g >> 12, pix = g & 4095;
    const int y = pix >> 6, x = pix & 63;
    const float* img = tm + (size_t)b * 4096;
    float v[3][3];
#pragma unroll
    for (int r = -1; r <= 1; r++)
#pragma unroll
      for (int c = -1; c <= 1; c++) {
        int yy = y + r, xx = x + c;
        v[r + 1][c + 1] = (yy >= 0 && yy < 64 && xx >= 0 && xx < 64) ? img[yy * 64 + xx] : 0.f;
      }
    float gx = (v[0][2] - v[0][0]) + 2.f * (v[1][2] - v[1][0]) + (v[2][2] - v[2][0]);
    float gy = (v[2][0] - v[0][0]) + 2.f * (v[2][1] - v[0][1]) + (v[2][2] - v[0][2]);
    float m = sqrtf(gx * gx + gy * gy);
    mag[g] = m;
    unsigned int mu = __float_as_uint(m);
    unsigned int mnu = mu, mxu = mu;
#pragma unroll
    for (int off = 32; off >= 1; off >>= 1) {
      mnu = min(mnu, __shfl_xor(mnu, off));
      mxu = max(mxu, __shfl_xor(mxu, off));
    }
    if ((tid & 63) == 0) {
      atomicMin(&mnmx[b], mnu);
      atomicMax(&mnmx[8 + b], mxu);
    }
  }
  // ---- G4: sn = normalize(Ws @ fs3), K=256 sequential (independent of G3) ----
  {
    const int w = tid >> 6, ln = tid & 63;
    const int o0 = w * 16;
    const int b = bx >> 6;
    const int pixl = (bx & 63) * 64 + ln;
    const float* fb = fs3 + (size_t)b * 1048576 + pixl;
    const float* wb = WsT + o0;
    float4 a4[4];
#pragma unroll
    for (int j = 0; j < 4; ++j) a4[j] = make_float4(0.f, 0.f, 0.f, 0.f);
    gemm_core<64, 4096>(fb, wb, a4);
    float ss = 0.f;
#pragma unroll
    for (int j = 0; j < 4; ++j)
      ss += a4[j].x * a4[j].x + a4[j].y * a4[j].y + a4[j].z * a4[j].z + a4[j].w * a4[j].w;
    float* ssq = fl;                                  // [4][64] scratch
    ssq[w * 64 + ln] = ss;
    __syncthreads();
    float tot = ssq[ln] + ssq[64 + ln] + ssq[128 + ln] + ssq[192 + ln];
    float rn = 1.f / fmaxf(sqrtf(tot), 1e-12f);
    float* ob = sn + ((size_t)b * 4096 + pixl) * 64 + o0;
#pragma unroll
    for (int j = 0; j < 4; ++j)
      *(float4*)(ob + 4 * j) = make_float4(a4[j].x * rn, a4[j].y * rn, a4[j].z * rn, a4[j].w * rn);
  }
  gridbar(bar, 3);

  // ---- G5: fused s+t affinities + log_softmax + gating + KL + reduce ----
  {
    const int wvu = __builtin_amdgcn_readfirstlane(tid >> 6);
    const int ln = tid & 63;
    const int b = bx >> 6, tl = bx & 63;
    const int ty0 = (tl >> 3) * 8, tx0 = (tl & 7) * 8;
    const int ty = ln >> 3, tx = ln & 7;
#pragma unroll
    for (int t2 = 0; t2 < 2; t2++) {
      const float* src = t2 ? tn : sn;
      float* dst = fl + t2 * 9792;
#pragma unroll
      for (int i = 0; i < 9; i++) {
        int flat = i * 256 + tid;
        int pos = flat >> 4, cg = flat & 15;
        int hy = pos / 12, hx = pos - hy * 12;
        int gy2 = reflect_idx(ty0 + hy - 2, 64);
        int gx2 = reflect_idx(tx0 + hx - 2, 64);
        float4 f = *(const float4*)(src + ((size_t)b * 4096 + gy2 * 64 + gx2) * 64 + cg * 4);
        int sw = (((pos * 17) >> 3) & 3) << 2;
        *(float4*)(&dst[pos * 68 + ((cg * 4) ^ sw)]) = f;
      }
    }
    __syncthreads();
    const int base = ty * 12 + tx;
    const int cbase = wvu * 16;
    float affs[24], afft[24];
    windows24(fl, base, cbase, affs);
    windows24(fl + 9792, base, cbase, afft);
    __syncthreads();                                  // staging dead -> reduce buffers
    float* rs = fl;
    float* rt = fl + 6400;
#pragma unroll
    for (int n = 0; n < 24; n++) {
      rs[(wvu * 64 + ln) * 25 + n] = affs[n];
      rt[(wvu * 64 + ln) * 25 + n] = afft[n];
    }
    __syncthreads();
    if (wvu == 0) {
      float as_[24], at_[24];
#pragma unroll
      for (int n = 0; n < 24; n++) {
        as_[n] = rs[ln * 25 + n] + rs[(64 + ln) * 25 + n] + rs[(128 + ln) * 25 + n] + rs[(192 + ln) * 25 + n];
        at_[n] = rt[ln * 25 + n] + rt[(64 + ln) * 25 + n] + rt[(128 + ln) * 25 + n] + rt[(192 + ln) * 25 + n];
      }
      float mxt = at_[0], mxs = as_[0];
#pragma unroll
      for (int n = 1; n < 24; n++) { mxt = fmaxf(mxt, at_[n]); mxs = fmaxf(mxs, as_[n]); }
      float et[24];
      float st = 0.f, ssum = 0.f;
#pragma unroll
      for (int n = 0; n < 24; n++) {
        et[n] = expf((at_[n] - mxt) * 10.f); st += et[n];
        ssum += expf((as_[n] - mxs) * 10.f);
      }
      float lset = logf(st), lses = logf(ssum);
      float rst = 1.f / st;
      float ent = 0.f, kl = 0.f;
#pragma unroll
      for (int n = 0; n < 24; n++) {
        float tp = et[n] * rst;
        float tlp = (at_[n] - mxt) * 10.f - lset;
        float slp = (as_[n] - mxs) * 10.f - lses;
        ent -= tp * tlp;
        kl += tp * (tlp - slp);
      }
      float wconf = 1.f - ent * (1.0f / 3.17805383034794580f);   // MAXH = log(24)
      wconf = fminf(fmaxf(wconf, 0.f), 1.f);
      const int gy = ty0 + ty, gx = tx0 + tx;
      const int gpix = b * 4096 + gy * 64 + gx;
      float mnv = __uint_as_float(mnmx[b]);
      float mxv = __uint_as_float(mnmx[8 + b]);
      float wedge = (mag[gpix] - mnv) / (mxv - mnv + 1e-6f);
      float wgt = wconf * wconf * (1.f + wedge);
      if (gy < 2 || gy >= 62 || gx < 2 || gx >= 62) wgt = 0.f;
      double wkl = (double)(wgt * kl), wsum = (double)wgt;
#pragma unroll
      for (int off = 32; off >= 1; off >>= 1) {
        wkl  += __shfl_down(wkl, off);
        wsum += __shfl_down(wsum, off);
      }
      if (ln == 0) {
        atomicAdd(&acc[0], wkl);
        atomicAdd(&acc[1], wsum);
      }
    }
  }
  gridbar(bar, 4);
  if (bx == 0 && tid == 0) out[0] = (float)(acc[0] / (acc[1] + 1e-6));
}

extern "C" void kernel_launch(void* const* d_in, const int* in_sizes, int n_in,
                              void* d_out, int out_size, void* d_ws, size_t ws_size,
                              hipStream_t stream) {
  const float* fs3 = (const float*)d_in[0];
  const float* ft  = (const float*)d_in[1];
  const float* Ws  = (const float*)d_in[2];
  const float* Wt  = (const float*)d_in[3];
  k_fused<<<NBLK, NTHR, 0, stream>>>(fs3, ft, Ws, Wt, (float*)d_ws, (float*)d_out);
}